// Round 1
// baseline (1172.756 us; speedup 1.0000x reference)
//
#include <hip/hip_runtime.h>

#define NEXP 32
#define HD   1024
#define FD   2048
#define NTOK 4096
#define CAP  512

typedef __attribute__((ext_vector_type(8))) short s8v;   // 8 x bf16 (4 VGPRs)
typedef __attribute__((ext_vector_type(4))) float f4v;   // 4 x fp32 acc

__device__ __forceinline__ unsigned short f2bf(float f) {
  unsigned u = __float_as_uint(f);
  u += 0x7fffu + ((u >> 16) & 1u);          // round-to-nearest-even
  return (unsigned short)(u >> 16);
}
__device__ __forceinline__ float bf2f(unsigned short h) {
  return __uint_as_float(((unsigned)h) << 16);
}

// ---------------- K1: router (fp32 exact), top-2, aux partials ----------------
// 4 waves/block, 4 tokens/wave (Wr loads amortized 4x). Selection done on raw
// fp32 logits (monotone == probs order) to match reference top-k picks.
__global__ __launch_bounds__(256) void router_kernel(
    const float* __restrict__ x, const float* __restrict__ Wr, const float* __restrict__ br,
    int* __restrict__ eidx, float* __restrict__ wts,
    float* __restrict__ probs_sum, int* __restrict__ cnt1)
{
  const int wid = threadIdx.x >> 6, lane = threadIdx.x & 63;
  const int t0 = blockIdx.x * 16 + wid * 4;
  __shared__ float ll[4][4][NEXP];
  __shared__ float ps[NEXP];
  __shared__ int   c1[NEXP];
  if (threadIdx.x < NEXP) { ps[threadIdx.x] = 0.f; c1[threadIdx.x] = 0; }
  __syncthreads();

  float xr[4][16];
  #pragma unroll
  for (int tk = 0; tk < 4; tk++) {
    const float* xp = x + (size_t)(t0 + tk) * HD + lane * 4;
    #pragma unroll
    for (int i = 0; i < 4; i++) {
      float4 v = *(const float4*)(xp + i * 256);
      xr[tk][i*4+0]=v.x; xr[tk][i*4+1]=v.y; xr[tk][i*4+2]=v.z; xr[tk][i*4+3]=v.w;
    }
  }
  for (int e = 0; e < NEXP; e++) {
    const float* wp = Wr + e * HD + lane * 4;
    float w[16];
    #pragma unroll
    for (int i = 0; i < 4; i++) {
      float4 v = *(const float4*)(wp + i * 256);
      w[i*4+0]=v.x; w[i*4+1]=v.y; w[i*4+2]=v.z; w[i*4+3]=v.w;
    }
    float s0=0.f,s1=0.f,s2=0.f,s3=0.f;
    #pragma unroll
    for (int i = 0; i < 16; i++) {
      s0 += xr[0][i]*w[i]; s1 += xr[1][i]*w[i];
      s2 += xr[2][i]*w[i]; s3 += xr[3][i]*w[i];
    }
    #pragma unroll
    for (int o = 32; o > 0; o >>= 1) {
      s0 += __shfl_xor(s0, o); s1 += __shfl_xor(s1, o);
      s2 += __shfl_xor(s2, o); s3 += __shfl_xor(s3, o);
    }
    if (lane == 0) {
      float b = br[e];
      ll[wid][0][e]=s0+b; ll[wid][1][e]=s1+b; ll[wid][2][e]=s2+b; ll[wid][3][e]=s3+b;
    }
  }
  __syncthreads();

  for (int tk = 0; tk < 4; tk++) {
    const int t = t0 + tk;
    float lg[NEXP];
    #pragma unroll
    for (int e = 0; e < NEXP; e++) lg[e] = ll[wid][tk][e];
    float mx = lg[0];
    #pragma unroll
    for (int e = 1; e < NEXP; e++) mx = fmaxf(mx, lg[e]);
    float pr[NEXP]; float den = 0.f;
    #pragma unroll
    for (int e = 0; e < NEXP; e++) { pr[e] = __expf(lg[e] - mx); den += pr[e]; }
    float inv = 1.f / den;
    #pragma unroll
    for (int e = 0; e < NEXP; e++) pr[e] *= inv;
    // top-2 on raw logits (exact fp32; ties -> lower index like jax top_k)
    int i1 = 0; float l1 = lg[0];
    #pragma unroll
    for (int e = 1; e < NEXP; e++) if (lg[e] > l1) { l1 = lg[e]; i1 = e; }
    int i2 = (i1 == 0) ? 1 : 0; float l2 = lg[i2];
    #pragma unroll
    for (int e = 0; e < NEXP; e++) if (e != i1 && lg[e] > l2) { l2 = lg[e]; i2 = e; }
    if (lane == 0) {
      float p1 = pr[i1], p2 = pr[i2];
      float ex = __expf(p2 - p1);               // softmax over the two prob values
      float w1 = 1.f / (1.f + ex);
      eidx[2*t] = i1; eidx[2*t+1] = i2;
      wts[2*t] = w1;  wts[2*t+1] = ex * w1;
      atomicAdd(&c1[i1], 1);
    }
    if (lane < NEXP) atomicAdd(&ps[lane], pr[lane]);
  }
  __syncthreads();
  if (threadIdx.x < NEXP) {
    atomicAdd(&probs_sum[threadIdx.x], ps[threadIdx.x]);
    atomicAdd(&cnt1[threadIdx.x], c1[threadIdx.x]);
  }
}

// ---------------- K2: capacity dispatch (stable counting scan) ----------------
// Single block. pos[i] = #earlier (t,k) entries routed to same expert; exact
// token-major first-come priority as the reference cumsum.
__global__ __launch_bounds__(256) void scan_kernel(
    const int* __restrict__ eidx, int* __restrict__ pos,
    int* __restrict__ slot_tok, int* __restrict__ cnt)
{
  __shared__ int lc[256 * NEXP];                 // [thread][expert], 32 KB
  const int tid = threadIdx.x;
  const int base = tid * NEXP;
  #pragma unroll
  for (int e = 0; e < NEXP; e++) lc[base + e] = 0;
  // count own chunk of 32 consecutive entries
  for (int j = 0; j < 32; j++) lc[base + eidx[tid * 32 + j]]++;
  __syncthreads();
  if (tid < NEXP) {                              // exclusive scan over chunks per expert
    int run = 0;
    for (int j = 0; j < 256; j++) {
      int v = lc[j * NEXP + tid];
      lc[j * NEXP + tid] = run;
      run += v;
    }
    cnt[tid] = run;
  }
  __syncthreads();
  for (int j = 0; j < 32; j++) {
    const int i = tid * 32 + j;
    const int e = eidx[i];
    const int p = lc[base + e]++;
    pos[i] = p;
    if (p < CAP) slot_tok[e * CAP + p] = i >> 1; // token id
  }
}

// ---------------- K3: gather x -> Xe (bf16), zero-pad to 128-row tiles --------
__global__ __launch_bounds__(256) void gather_kernel(
    const float* __restrict__ x, const int* __restrict__ slot_tok,
    const int* __restrict__ cnt, unsigned short* __restrict__ Xe)
{
  const int e = blockIdx.y, row = blockIdx.x;
  const int ne = min(cnt[e], CAP);
  const int npad = (ne + 127) & ~127;
  if (row >= npad) return;
  const int h = threadIdx.x * 4;
  unsigned short* dst = Xe + ((size_t)e * CAP + row) * HD + h;
  if (row < ne) {
    const int t = slot_tok[e * CAP + row];
    float4 v = *(const float4*)(x + (size_t)t * HD + h);
    ushort4 o; o.x = f2bf(v.x); o.y = f2bf(v.y); o.z = f2bf(v.z); o.w = f2bf(v.w);
    *(ushort4*)dst = o;
  } else {
    *(ushort4*)dst = make_ushort4(0, 0, 0, 0);
  }
}

// ---------------- K4/K5: tiled bf16 MFMA GEMM -------------------------------
// C[m,n] = sum_k A[m,k]*B[k,n] per expert. A bf16 [CAP][KDIM]; B fp32 [KDIM][NDIM]
// converted to bf16 during staging. B is N-contiguous, MFMA wants K-contiguous
// fragments -> two-stage LDS transpose (row-major stage, 8x ds_read_u16 column
// gather, b128 write to [n][k]). NMAT=2: dual acc (g,u) + SwiGLU epilogue.
// MFMA 16x16x32 bf16 layouts (HW-verified per guide):
//   A: m=lane&15, k=(lane>>4)*8+j ; B: n=lane&15, k=(lane>>4)*8+j
//   C/D: col=lane&15, row=(lane>>4)*4+reg
template<int NMAT, int KDIM, int NDIM>
__global__ __launch_bounds__(256, 1) void gemm_kernel(
    const unsigned short* __restrict__ A, const float* __restrict__ B0,
    const float* __restrict__ B1, unsigned short* __restrict__ C,
    const int* __restrict__ cnt)
{
  const int e  = blockIdx.z;
  const int m0 = blockIdx.y * 128;
  const int n0 = blockIdx.x * 128;
  const int ne = min(cnt[e], CAP);
  if (m0 >= ne) return;

  __shared__ __align__(16) unsigned short As[128][40];          // [m][k], pad->free
  __shared__ __align__(16) unsigned short Bs[NMAT][128][40];    // [n][k] transposed
  __shared__ __align__(16) unsigned short Bst[NMAT][32][136];   // [k][n] stage

  const int tid = threadIdx.x;
  const int lane = tid & 63;
  const int wid = tid >> 6;
  const int wm = (wid >> 1) * 64, wn = (wid & 1) * 64;

  f4v acc[NMAT][4][4];
  #pragma unroll
  for (int m = 0; m < NMAT; m++)
    #pragma unroll
    for (int i = 0; i < 4; i++)
      #pragma unroll
      for (int j = 0; j < 4; j++)
        acc[m][i][j] = (f4v){0.f, 0.f, 0.f, 0.f};

  const unsigned short* Ae = A + ((size_t)e * CAP + m0) * KDIM;
  const float* bp0 = B0 + (size_t)e * KDIM * NDIM + n0;
  const float* bp1 = (NMAT == 2) ? (B1 + (size_t)e * KDIM * NDIM + n0) : bp0;

  for (int k0 = 0; k0 < KDIM; k0 += 32) {
    // phase 1: stage B fp32 -> bf16 row-major [k][n]
    #pragma unroll
    for (int mat = 0; mat < NMAT; mat++) {
      const float* bp = ((mat == 0) ? bp0 : bp1) + (size_t)k0 * NDIM;
      #pragma unroll
      for (int s = 0; s < 4; s++) {
        const int c = tid + 256 * s;
        const int kk = c >> 5, n4 = (c & 31) * 4;
        float4 v = *(const float4*)(bp + kk * NDIM + n4);
        uint2 pk;
        pk.x = f2bf(v.x) | ((unsigned)f2bf(v.y) << 16);
        pk.y = f2bf(v.z) | ((unsigned)f2bf(v.w) << 16);
        *(uint2*)&Bst[mat][kk][n4] = pk;
      }
    }
    __syncthreads();
    // phase 2a: A tile (already bf16) -> LDS
    #pragma unroll
    for (int s = 0; s < 2; s++) {
      const int c = tid + 256 * s;
      const int row = c >> 2, cc = (c & 3) * 8;
      uint4 v = *(const uint4*)(Ae + (size_t)row * KDIM + k0 + cc);
      *(uint4*)&As[row][cc] = v;
    }
    // phase 2b: transpose B into [n][k]
    #pragma unroll
    for (int mat = 0; mat < NMAT; mat++) {
      #pragma unroll
      for (int s = 0; s < 2; s++) {
        const int task = tid + 256 * s;
        const int n = task & 127, oct = (task >> 7) * 8;
        unsigned v0 = Bst[mat][oct+0][n] | ((unsigned)Bst[mat][oct+1][n] << 16);
        unsigned v1 = Bst[mat][oct+2][n] | ((unsigned)Bst[mat][oct+3][n] << 16);
        unsigned v2 = Bst[mat][oct+4][n] | ((unsigned)Bst[mat][oct+5][n] << 16);
        unsigned v3 = Bst[mat][oct+6][n] | ((unsigned)Bst[mat][oct+7][n] << 16);
        *(uint4*)&Bs[mat][n][oct] = make_uint4(v0, v1, v2, v3);
      }
    }
    __syncthreads();
    // fragments + MFMA
    s8v af[4];
    #pragma unroll
    for (int fm = 0; fm < 4; fm++)
      af[fm] = *(const s8v*)&As[wm + fm * 16 + (lane & 15)][(lane >> 4) * 8];
    #pragma unroll
    for (int mat = 0; mat < NMAT; mat++) {
      #pragma unroll
      for (int fn = 0; fn < 4; fn++) {
        s8v bfr = *(const s8v*)&Bs[mat][wn + fn * 16 + (lane & 15)][(lane >> 4) * 8];
        #pragma unroll
        for (int fm = 0; fm < 4; fm++)
          acc[mat][fm][fn] = __builtin_amdgcn_mfma_f32_16x16x32_bf16(
              af[fm], bfr, acc[mat][fm][fn], 0, 0, 0);
      }
    }
    // next iteration's first __syncthreads() provides the needed separation
  }

  const int roff = (lane >> 4) * 4, coff = lane & 15;
  #pragma unroll
  for (int fm = 0; fm < 4; fm++) {
    #pragma unroll
    for (int fn = 0; fn < 4; fn++) {
      #pragma unroll
      for (int r = 0; r < 4; r++) {
        const int row = m0 + wm + fm * 16 + roff + r;
        const int col = n0 + wn + fn * 16 + coff;
        float val;
        if (NMAT == 2) {
          float g = acc[0][fm][fn][r], u = acc[1][fm][fn][r];
          val = (g / (1.f + __expf(-g))) * u;     // silu(g)*u
        } else {
          val = acc[0][fm][fn][r];
        }
        C[((size_t)e * CAP + row) * NDIM + col] = f2bf(val);
      }
    }
  }
}

// ---------------- K6: combine + aux loss -------------------------------------
__global__ __launch_bounds__(256) void combine_kernel(
    const unsigned short* __restrict__ y, const int* __restrict__ eidx,
    const float* __restrict__ wts, const int* __restrict__ pos,
    const float* __restrict__ ps, const int* __restrict__ c1,
    float* __restrict__ out)
{
  const int t = blockIdx.x;
  const int h = threadIdx.x * 4;
  float a0 = 0.f, a1 = 0.f, a2 = 0.f, a3 = 0.f;
  #pragma unroll
  for (int k = 0; k < 2; k++) {
    const int i = 2 * t + k;
    const int p = pos[i];
    if (p < CAP) {
      const int e = eidx[i];
      const float w = wts[i];
      ushort4 v = *(const ushort4*)(y + ((size_t)e * CAP + p) * HD + h);
      a0 += w * bf2f(v.x); a1 += w * bf2f(v.y);
      a2 += w * bf2f(v.z); a3 += w * bf2f(v.w);
    }
  }
  *(float4*)(out + (size_t)t * HD + h) = make_float4(a0, a1, a2, a3);
  if (t == 0 && threadIdx.x == 0) {
    float a = 0.f;
    for (int e = 0; e < NEXP; e++) a += ps[e] * (float)c1[e];
    out[(size_t)NTOK * HD] = a * (32.f * 0.01f / (4096.f * 4096.f));
  }
}

// ---------------- launch ------------------------------------------------------
extern "C" void kernel_launch(void* const* d_in, const int* in_sizes, int n_in,
                              void* d_out, int out_size, void* d_ws, size_t ws_size,
                              hipStream_t stream) {
  const float* x  = (const float*)d_in[0];
  const float* Wr = (const float*)d_in[1];
  const float* br = (const float*)d_in[2];
  const float* Wg = (const float*)d_in[3];
  const float* Wu = (const float*)d_in[4];
  const float* Wd = (const float*)d_in[5];
  float* out = (float*)d_out;

  // ws layout (needs ~134.4 MB)
  char* ws = (char*)d_ws;
  unsigned short* Xe  = (unsigned short*)(ws);               // 32*512*1024 bf16
  unsigned short* hid = (unsigned short*)(ws + 33554432);    // 32*512*2048 bf16
  unsigned short* yb  = (unsigned short*)(ws + 100663296);   // 32*512*1024 bf16
  int*   eidx = (int*)  (ws + 134217728);                    // 8192
  float* wts  = (float*)(ws + 134250496);                    // 8192
  int*   pos  = (int*)  (ws + 134283264);                    // 8192
  int*   slot = (int*)  (ws + 134316032);                    // 32*512
  int*   cnt  = (int*)  (ws + 134381568);                    // 32
  float* ps   = (float*)(ws + 134381696);                    // 32
  int*   c1   = (int*)  (ws + 134381824);                    // 32

  hipMemsetAsync(ws + 134381696, 0, 256, stream);            // zero ps + c1

  router_kernel<<<256, 256, 0, stream>>>(x, Wr, br, eidx, wts, ps, c1);
  scan_kernel<<<1, 256, 0, stream>>>(eidx, pos, slot, cnt);
  gather_kernel<<<dim3(CAP, NEXP), 256, 0, stream>>>(x, slot, cnt, Xe);
  gemm_kernel<2, HD, FD><<<dim3(FD / 128, CAP / 128, NEXP), 256, 0, stream>>>(
      Xe, Wg, Wu, hid, cnt);
  gemm_kernel<1, FD, HD><<<dim3(HD / 128, CAP / 128, NEXP), 256, 0, stream>>>(
      hid, Wd, nullptr, yb, cnt);
  combine_kernel<<<NTOK, 256, 0, stream>>>(yb, eidx, wts, pos, ps, c1, out);
}

// Round 2
// 1108.325 us; speedup vs baseline: 1.0581x; 1.0581x over previous
//
#include <hip/hip_runtime.h>

#define NEXP 32
#define HD   1024
#define FD   2048
#define NTOK 4096
#define CAP  512

typedef __attribute__((ext_vector_type(8))) short s8v;   // 8 x bf16 (4 VGPRs)
typedef __attribute__((ext_vector_type(4))) float f4v;   // 4 x fp32 acc

__device__ __forceinline__ unsigned short f2bf(float f) {
  unsigned u = __float_as_uint(f);
  u += 0x7fffu + ((u >> 16) & 1u);          // round-to-nearest-even
  return (unsigned short)(u >> 16);
}
__device__ __forceinline__ float bf2f(unsigned short h) {
  return __uint_as_float(((unsigned)h) << 16);
}

// async global->LDS 16B/lane; LDS dest = wave-uniform base + lane*16
#define GLL16(gp, lp) __builtin_amdgcn_global_load_lds( \
    (const __attribute__((address_space(1))) unsigned int*)(gp), \
    (__attribute__((address_space(3))) unsigned int*)(lp), 16, 0, 0)

// ---------------- K0: weight transpose+convert  fp32[E][K][N] -> bf16[E][N][K]
// 64x64 tiles; coalesced fp32 reads, coalesced bf16 writes; LDS stride 66
// halves keeps both phases <=2-way on banks. HBM-bound streaming pass.
template<int K, int N>
__global__ __launch_bounds__(256) void transpose_kernel(
    const float* __restrict__ in, unsigned short* __restrict__ outp)
{
  __shared__ unsigned short lds[64 * 66];
  const int e = blockIdx.z;
  const int k0 = blockIdx.y * 64, n0 = blockIdx.x * 64;
  const float* ip = in + (size_t)e * K * N + (size_t)k0 * N + n0;
  unsigned short* op = outp + (size_t)e * N * K + (size_t)n0 * K + k0;
  const int t = threadIdx.x;
  const int kk = t >> 4, nn = (t & 15) * 4;
  #pragma unroll
  for (int i = 0; i < 4; i++) {
    const int k = kk + i * 16;
    float4 v = *(const float4*)(ip + (size_t)k * N + nn);
    uint2 pk;
    pk.x = f2bf(v.x) | ((unsigned)f2bf(v.y) << 16);
    pk.y = f2bf(v.z) | ((unsigned)f2bf(v.w) << 16);
    *(uint2*)&lds[k * 66 + nn] = pk;
  }
  __syncthreads();
  const int n_r = t >> 4, k4 = (t & 15) * 4;
  #pragma unroll
  for (int i = 0; i < 4; i++) {
    const int n = n_r + i * 16;
    ushort4 o;
    o.x = lds[(k4 + 0) * 66 + n];
    o.y = lds[(k4 + 1) * 66 + n];
    o.z = lds[(k4 + 2) * 66 + n];
    o.w = lds[(k4 + 3) * 66 + n];
    *(ushort4*)(op + (size_t)n * K + k4) = o;
  }
}

// ---------------- K1: router (fp32 exact), top-2, aux partials ----------------
__global__ __launch_bounds__(256) void router_kernel(
    const float* __restrict__ x, const float* __restrict__ Wr, const float* __restrict__ br,
    int* __restrict__ eidx, float* __restrict__ wts,
    float* __restrict__ probs_sum, int* __restrict__ cnt1)
{
  const int wid = threadIdx.x >> 6, lane = threadIdx.x & 63;
  const int t0 = blockIdx.x * 16 + wid * 4;
  __shared__ float ll[4][4][NEXP];
  __shared__ float ps[NEXP];
  __shared__ int   c1[NEXP];
  if (threadIdx.x < NEXP) { ps[threadIdx.x] = 0.f; c1[threadIdx.x] = 0; }
  __syncthreads();

  float xr[4][16];
  #pragma unroll
  for (int tk = 0; tk < 4; tk++) {
    const float* xp = x + (size_t)(t0 + tk) * HD + lane * 4;
    #pragma unroll
    for (int i = 0; i < 4; i++) {
      float4 v = *(const float4*)(xp + i * 256);
      xr[tk][i*4+0]=v.x; xr[tk][i*4+1]=v.y; xr[tk][i*4+2]=v.z; xr[tk][i*4+3]=v.w;
    }
  }
  for (int e = 0; e < NEXP; e++) {
    const float* wp = Wr + e * HD + lane * 4;
    float w[16];
    #pragma unroll
    for (int i = 0; i < 4; i++) {
      float4 v = *(const float4*)(wp + i * 256);
      w[i*4+0]=v.x; w[i*4+1]=v.y; w[i*4+2]=v.z; w[i*4+3]=v.w;
    }
    float s0=0.f,s1=0.f,s2=0.f,s3=0.f;
    #pragma unroll
    for (int i = 0; i < 16; i++) {
      s0 += xr[0][i]*w[i]; s1 += xr[1][i]*w[i];
      s2 += xr[2][i]*w[i]; s3 += xr[3][i]*w[i];
    }
    #pragma unroll
    for (int o = 32; o > 0; o >>= 1) {
      s0 += __shfl_xor(s0, o); s1 += __shfl_xor(s1, o);
      s2 += __shfl_xor(s2, o); s3 += __shfl_xor(s3, o);
    }
    if (lane == 0) {
      float b = br[e];
      ll[wid][0][e]=s0+b; ll[wid][1][e]=s1+b; ll[wid][2][e]=s2+b; ll[wid][3][e]=s3+b;
    }
  }
  __syncthreads();

  for (int tk = 0; tk < 4; tk++) {
    const int t = t0 + tk;
    float lg[NEXP];
    #pragma unroll
    for (int e = 0; e < NEXP; e++) lg[e] = ll[wid][tk][e];
    float mx = lg[0];
    #pragma unroll
    for (int e = 1; e < NEXP; e++) mx = fmaxf(mx, lg[e]);
    float pr[NEXP]; float den = 0.f;
    #pragma unroll
    for (int e = 0; e < NEXP; e++) { pr[e] = __expf(lg[e] - mx); den += pr[e]; }
    float inv = 1.f / den;
    #pragma unroll
    for (int e = 0; e < NEXP; e++) pr[e] *= inv;
    int i1 = 0; float l1 = lg[0];
    #pragma unroll
    for (int e = 1; e < NEXP; e++) if (lg[e] > l1) { l1 = lg[e]; i1 = e; }
    int i2 = (i1 == 0) ? 1 : 0; float l2 = lg[i2];
    #pragma unroll
    for (int e = 0; e < NEXP; e++) if (e != i1 && lg[e] > l2) { l2 = lg[e]; i2 = e; }
    if (lane == 0) {
      float p1 = pr[i1], p2 = pr[i2];
      float ex = __expf(p2 - p1);
      float w1 = 1.f / (1.f + ex);
      eidx[2*t] = i1; eidx[2*t+1] = i2;
      wts[2*t] = w1;  wts[2*t+1] = ex * w1;
      atomicAdd(&c1[i1], 1);
    }
    if (lane < NEXP) atomicAdd(&ps[lane], pr[lane]);
  }
  __syncthreads();
  if (threadIdx.x < NEXP) {
    atomicAdd(&probs_sum[threadIdx.x], ps[threadIdx.x]);
    atomicAdd(&cnt1[threadIdx.x], c1[threadIdx.x]);
  }
}

// ---------------- K2: capacity dispatch (stable counting scan) ----------------
__global__ __launch_bounds__(256) void scan_kernel(
    const int* __restrict__ eidx, int* __restrict__ pos,
    int* __restrict__ slot_tok, int* __restrict__ cnt)
{
  __shared__ int lc[256 * NEXP];
  const int tid = threadIdx.x;
  const int base = tid * NEXP;
  #pragma unroll
  for (int e = 0; e < NEXP; e++) lc[base + e] = 0;
  for (int j = 0; j < 32; j++) lc[base + eidx[tid * 32 + j]]++;
  __syncthreads();
  if (tid < NEXP) {
    int run = 0;
    for (int j = 0; j < 256; j++) {
      int v = lc[j * NEXP + tid];
      lc[j * NEXP + tid] = run;
      run += v;
    }
    cnt[tid] = run;
  }
  __syncthreads();
  for (int j = 0; j < 32; j++) {
    const int i = tid * 32 + j;
    const int e = eidx[i];
    const int p = lc[base + e]++;
    pos[i] = p;
    if (p < CAP) slot_tok[e * CAP + p] = i >> 1;
  }
}

// ---------------- K3: gather x -> Xe (bf16), zero-pad to 128-row tiles --------
__global__ __launch_bounds__(256) void gather_kernel(
    const float* __restrict__ x, const int* __restrict__ slot_tok,
    const int* __restrict__ cnt, unsigned short* __restrict__ Xe)
{
  const int e = blockIdx.y, row = blockIdx.x;
  const int ne = min(cnt[e], CAP);
  const int npad = (ne + 127) & ~127;
  if (row >= npad) return;
  const int h = threadIdx.x * 4;
  unsigned short* dst = Xe + ((size_t)e * CAP + row) * HD + h;
  if (row < ne) {
    const int t = slot_tok[e * CAP + row];
    float4 v = *(const float4*)(x + (size_t)t * HD + h);
    ushort4 o; o.x = f2bf(v.x); o.y = f2bf(v.y); o.z = f2bf(v.z); o.w = f2bf(v.w);
    *(ushort4*)dst = o;
  } else {
    *(ushort4*)dst = make_ushort4(0, 0, 0, 0);
  }
}

// ---------------- K4/K5: m97-style bf16 MFMA GEMM ----------------------------
// A [E][CAP][KDIM] bf16 K-contig; B [E][NDIM][KDIM] bf16 K-contig (pre-
// transposed). Tile 128 x TN, BK=64. Both operands staged via
// global_load_lds_dwordx4 with XOR-8 chunk swizzle (pos = chunk ^ (row&7)):
// rows are 128B = 32 banks, so swizzled b128 fragment reads are conflict-free.
// NMAT=2 fuses SwiGLU (g,u dual-accumulate) in the epilogue.
// MFMA 16x16x32 bf16 layouts: A/B: m|n=lane&15, k=(lane>>4)*8+j;
// C/D: col=lane&15, row=(lane>>4)*4+reg.
template<int NMAT, int KDIM, int NDIM, int TN>
__global__ __launch_bounds__(256) void gemm_kernel(
    const unsigned short* __restrict__ A, const unsigned short* __restrict__ B0,
    const unsigned short* __restrict__ B1, unsigned short* __restrict__ C,
    const int* __restrict__ cnt)
{
  constexpr int FN = TN / 32;              // 16-col frags per wave
  const int e = blockIdx.z;
  const int ne = min(cnt[e], CAP);
  const int m0 = blockIdx.x * 128;         // m fastest: M-tiles sharing a
  if (m0 >= ne) return;                    // B-tile dispatch adjacently (L2/L3)
  const int n0 = blockIdx.y * TN;

  __shared__ __align__(16) unsigned short As[128 * 64];
  __shared__ __align__(16) unsigned short Bs[NMAT][TN * 64];

  const int tid = threadIdx.x;
  const int lane = tid & 63, wid = tid >> 6;
  const int wm = (wid >> 1) * 64;
  const int wn = (wid & 1) * (TN / 2);
  const int l8 = lane >> 3;                // row within an 8-row group
  const int gch = (lane & 7) ^ l8;         // swizzled source 16B-chunk
  const int quad = lane >> 4, fr = lane & 15, x7 = lane & 7;

  f4v acc[NMAT][4][FN];
  #pragma unroll
  for (int m = 0; m < NMAT; m++)
    #pragma unroll
    for (int i = 0; i < 4; i++)
      #pragma unroll
      for (int j = 0; j < FN; j++)
        acc[m][i][j] = (f4v){0.f, 0.f, 0.f, 0.f};

  const unsigned short* Ae  = A  + ((size_t)e * CAP + m0) * KDIM;
  const unsigned short* Bp0 = B0 + ((size_t)e * NDIM + n0) * KDIM;
  const unsigned short* Bp1 = B1 + ((size_t)e * NDIM + n0) * KDIM;

  for (int k0 = 0; k0 < KDIM; k0 += 64) {
    #pragma unroll
    for (int j = 0; j < 4; j++) {          // A: 128 rows, 32/wave
      const int r = wid * 32 + j * 8 + l8;
      GLL16(Ae + (size_t)r * KDIM + k0 + gch * 8, &As[(wid * 32 + j * 8) * 64]);
    }
    #pragma unroll
    for (int mat = 0; mat < NMAT; mat++) { // B: TN rows, TN/4 per wave
      const unsigned short* Bp = mat ? Bp1 : Bp0;
      #pragma unroll
      for (int j = 0; j < TN / 32; j++) {
        const int r = wid * (TN / 4) + j * 8 + l8;
        GLL16(Bp + (size_t)r * KDIM + k0 + gch * 8,
              &Bs[mat][(wid * (TN / 4) + j * 8) * 64]);
      }
    }
    __syncthreads();
    #pragma unroll
    for (int kc = 0; kc < 2; kc++) {
      const int pos8 = ((kc * 4 + quad) ^ x7) * 8;
      s8v af[4];
      #pragma unroll
      for (int fm = 0; fm < 4; fm++)
        af[fm] = *(const s8v*)&As[(wm + fm * 16 + fr) * 64 + pos8];
      #pragma unroll
      for (int mat = 0; mat < NMAT; mat++)
        #pragma unroll
        for (int fn = 0; fn < FN; fn++) {
          s8v bfr = *(const s8v*)&Bs[mat][(wn + fn * 16 + fr) * 64 + pos8];
          #pragma unroll
          for (int fm = 0; fm < 4; fm++)
            acc[mat][fm][fn] = __builtin_amdgcn_mfma_f32_16x16x32_bf16(
                af[fm], bfr, acc[mat][fm][fn], 0, 0, 0);
        }
    }
    __syncthreads();
  }

  #pragma unroll
  for (int fm = 0; fm < 4; fm++)
    #pragma unroll
    for (int fn = 0; fn < FN; fn++)
      #pragma unroll
      for (int r = 0; r < 4; r++) {
        const int row = m0 + wm + fm * 16 + quad * 4 + r;
        const int col = n0 + wn + fn * 16 + fr;
        float v;
        if (NMAT == 2) {
          float g = acc[0][fm][fn][r], u = acc[1][fm][fn][r];
          v = (g / (1.f + __expf(-g))) * u;            // silu(g)*u
        } else {
          v = acc[0][fm][fn][r];
        }
        C[((size_t)e * CAP + row) * NDIM + col] = f2bf(v);
      }
}

// ---------------- K6: combine + aux loss -------------------------------------
__global__ __launch_bounds__(256) void combine_kernel(
    const unsigned short* __restrict__ y, const int* __restrict__ eidx,
    const float* __restrict__ wts, const int* __restrict__ pos,
    const float* __restrict__ ps, const int* __restrict__ c1,
    float* __restrict__ out)
{
  const int t = blockIdx.x;
  const int h = threadIdx.x * 4;
  float a0 = 0.f, a1 = 0.f, a2 = 0.f, a3 = 0.f;
  #pragma unroll
  for (int k = 0; k < 2; k++) {
    const int i = 2 * t + k;
    const int p = pos[i];
    if (p < CAP) {
      const int e = eidx[i];
      const float w = wts[i];
      ushort4 v = *(const ushort4*)(y + ((size_t)e * CAP + p) * HD + h);
      a0 += w * bf2f(v.x); a1 += w * bf2f(v.y);
      a2 += w * bf2f(v.z); a3 += w * bf2f(v.w);
    }
  }
  *(float4*)(out + (size_t)t * HD + h) = make_float4(a0, a1, a2, a3);
  if (t == 0 && threadIdx.x == 0) {
    float a = 0.f;
    for (int e = 0; e < NEXP; e++) a += ps[e] * (float)c1[e];
    out[(size_t)NTOK * HD] = a * (32.f * 0.01f / (4096.f * 4096.f));
  }
}

// ---------------- launch ------------------------------------------------------
extern "C" void kernel_launch(void* const* d_in, const int* in_sizes, int n_in,
                              void* d_out, int out_size, void* d_ws, size_t ws_size,
                              hipStream_t stream) {
  const float* x  = (const float*)d_in[0];
  const float* Wr = (const float*)d_in[1];
  const float* br = (const float*)d_in[2];
  const float* Wg = (const float*)d_in[3];
  const float* Wu = (const float*)d_in[4];
  const float* Wd = (const float*)d_in[5];
  float* out = (float*)d_out;

  // ws layout (~384.2 MB peak):
  //   [0,128M):    WT0 = Wg_t, later reused as Wd_t
  //   [128M,256M): WT1 = Wu_t
  //   [256M,288M): Xe bf16 [E][CAP][HD]
  //   [288M,352M): hid bf16 [E][CAP][FD]
  //   [352M,384M): yb bf16 [E][CAP][HD]
  //   [384M,...):  small buffers
  char* ws = (char*)d_ws;
  const size_t MB = 1048576;
  unsigned short* WT0 = (unsigned short*)(ws);
  unsigned short* WT1 = (unsigned short*)(ws + 128 * MB);
  unsigned short* Xe  = (unsigned short*)(ws + 256 * MB);
  unsigned short* hid = (unsigned short*)(ws + 288 * MB);
  unsigned short* yb  = (unsigned short*)(ws + 352 * MB);
  char* sm = ws + 384 * MB;
  int*   eidx = (int*)  (sm);              // 8192 ints
  float* wts  = (float*)(sm + 32768);      // 8192 f
  int*   pos  = (int*)  (sm + 65536);      // 8192 ints
  int*   slot = (int*)  (sm + 98304);      // 16384 ints
  int*   cnt  = (int*)  (sm + 163840);     // 32 ints
  float* ps   = (float*)(sm + 163968);     // 32 f
  int*   c1   = (int*)  (sm + 164096);     // 32 ints

  hipMemsetAsync(sm + 163968, 0, 256, stream);   // zero ps + c1

  // weight transposes (HBM-streaming)
  transpose_kernel<HD, FD><<<dim3(FD/64, HD/64, NEXP), 256, 0, stream>>>(Wg, WT0);
  transpose_kernel<HD, FD><<<dim3(FD/64, HD/64, NEXP), 256, 0, stream>>>(Wu, WT1);

  router_kernel<<<NTOK/16, 256, 0, stream>>>(x, Wr, br, eidx, wts, ps, c1);
  scan_kernel<<<1, 256, 0, stream>>>(eidx, pos, slot, cnt);
  gather_kernel<<<dim3(CAP, NEXP), 256, 0, stream>>>(x, slot, cnt, Xe);

  // SwiGLU GEMM: [E] ne x FD = (ne x HD) @ (HD x FD) twice, fused silu*u
  gemm_kernel<2, HD, FD, 64><<<dim3(CAP/128, FD/64, NEXP), 256, 0, stream>>>(
      Xe, WT0, WT1, hid, cnt);

  // Wd transpose into WT0 (Wg_t dead after GEMM1), then down-proj GEMM
  transpose_kernel<FD, HD><<<dim3(HD/64, FD/64, NEXP), 256, 0, stream>>>(Wd, WT0);
  gemm_kernel<1, FD, HD, 128><<<dim3(CAP/128, HD/128, NEXP), 256, 0, stream>>>(
      hid, WT0, WT0, yb, cnt);

  combine_kernel<<<NTOK, 256, 0, stream>>>(yb, eidx, wts, pos, ps, c1, out);
}